// Round 7
// baseline (792.607 us; speedup 1.0000x reference)
//
#include <hip/hip_runtime.h>
#include <hip/hip_bf16.h>

// Model dims: B=8, S=256, C=4, L=256, E=256, H=8, DH=32, NL=2, NS=8

typedef float floatx4 __attribute__((ext_vector_type(4)));
typedef short bf16x8 __attribute__((ext_vector_type(8)));

__device__ __forceinline__ float wave_sum(float v) {
    v += __shfl_xor(v, 32); v += __shfl_xor(v, 16); v += __shfl_xor(v, 8);
    v += __shfl_xor(v, 4);  v += __shfl_xor(v, 2);  v += __shfl_xor(v, 1);
    return v;
}
__device__ __forceinline__ float wave_max(float v) {
    v = fmaxf(v, __shfl_xor(v, 32)); v = fmaxf(v, __shfl_xor(v, 16));
    v = fmaxf(v, __shfl_xor(v, 8));  v = fmaxf(v, __shfl_xor(v, 4));
    v = fmaxf(v, __shfl_xor(v, 2));  v = fmaxf(v, __shfl_xor(v, 1));
    return v;
}
__device__ __forceinline__ unsigned short f2bf(float v) {
    unsigned b = __float_as_uint(v);
    unsigned r = (b + 0x7fffu + ((b >> 16) & 1u)) >> 16;
    return (unsigned short)r;
}

__global__ void init_kernel(unsigned* dmax, unsigned* cnnmax) {
    const size_t i = (size_t)blockIdx.x * 256 + threadIdx.x;
    cnnmax[i] = 0u;
    if (i == 0) *dmax = 0u;
}

// w2 [S][256co][128ci][3tap] fp32 -> fragment-linear bf16:
// w2f[s_l][wm(4)][kc(12)][r(4)][lane(64)][e(8)]  (A-frag for MFMA is 1KB contiguous)
// co = wm*64 + r*16 + (lane&15); kk = kc*32 + (lane>>4)*8 + e; tap=kk>>7; ci=kk&127
__global__ __launch_bounds__(256) void prep_w2_kernel(
    const float* __restrict__ w2, unsigned short* __restrict__ w2f, int s0)
{
    const int s_l = blockIdx.x;
    const int part = blockIdx.y;   // 0..7
    const int s = s0 + s_l;
    unsigned short* dst = w2f + (size_t)s_l * 98304;
    const float* src = w2 + (size_t)s * 98304;
    for (int o = part * 12288 + threadIdx.x; o < (part + 1) * 12288; o += 256) {
        const int e = o & 7;
        const int ln = (o >> 3) & 63;
        const int fr = o >> 9;            // 0..191
        const int r = fr & 3;
        const int kcwm = fr >> 2;         // 0..47
        const int kc = kcwm % 12;
        const int wm = kcwm / 12;
        const int lr = ln & 15, quad = ln >> 4;
        const int co = wm * 64 + r * 16 + lr;
        const int kk = kc * 32 + quad * 8 + e;
        const int tap = kk >> 7, ci = kk & 127;
        dst[o] = f2bf(src[(size_t)co * 384 + ci * 3 + tap]);
    }
}

// conv1 per (s_l, b): x[4][256] -> h1 bf16 stored as h1b[s_l][m=b*256+l][ci]
__global__ __launch_bounds__(256) void conv1_kernel(
    const float* __restrict__ x, const float* __restrict__ w1, const float* __restrict__ b1,
    unsigned short* __restrict__ h1b, int s0)
{
    __shared__ float xs[4][258];
    __shared__ float w1s[1536];
    __shared__ float h1c[128][65];
    const int tid = threadIdx.x;
    const int lane = tid & 63;
    const int grp = __builtin_amdgcn_readfirstlane((int)(tid >> 6));
    const int s_l = blockIdx.x;
    const int b = blockIdx.y;
    const int s = s0 + s_l;
    const int bs = b * 256 + s;

    const float* xp = x + (size_t)bs * 1024;
    for (int ci = 0; ci < 4; ci++) xs[ci][tid + 1] = xp[ci * 256 + tid];
    if (tid < 4) { xs[tid][0] = 0.f; xs[tid][257] = 0.f; }
    const float* w1p = w1 + (size_t)s * 1536;
    for (int i = tid; i < 1536; i += 256) w1s[i] = w1p[i];
    const float* b1p = b1 + s * 128;
    __syncthreads();

    const int ci2 = (tid & 63) * 2;
    const int q = tid >> 6;
    unsigned short* hb = h1b + ((size_t)(s_l * 2048 + b * 256)) * 128;

    for (int c = 0; c < 4; c++) {
        const int l0 = c * 64;
        if (c) __syncthreads();
        {
            float xr[4][3];
            const int l = l0 + lane;
#pragma unroll
            for (int ci = 0; ci < 4; ci++)
#pragma unroll
                for (int k = 0; k < 3; k++) xr[ci][k] = xs[ci][l + k];
            for (int it = 0; it < 32; it++) {
                const int co = grp + it * 4;
                float a = b1p[co];
                const float* w = &w1s[co * 12];
#pragma unroll
                for (int ci = 0; ci < 4; ci++)
#pragma unroll
                    for (int k = 0; k < 3; k++) a = fmaf(w[ci * 3 + k], xr[ci][k], a);
                h1c[co][lane] = fmaxf(a, 0.f);
            }
        }
        __syncthreads();
#pragma unroll
        for (int i = 0; i < 16; i++) {
            const int l_loc = q * 16 + i;
            const unsigned u0 = f2bf(h1c[ci2][l_loc]);
            const unsigned u1 = f2bf(h1c[ci2 + 1][l_loc]);
            *(unsigned*)(hb + (size_t)(l0 + l_loc) * 128 + ci2) = u0 | (u1 << 16);
        }
    }
}

// conv2 implicit GEMM, bf16 MFMA. B in padded LDS (r6 body); A-frags from
// fragment-linear w2f via rotating 6-chunk register prefetch (all loads
// contiguous 1KB). Grid (s_l, nt) keeps all 16 m-tiles of a segment on one XCD.
__global__ __launch_bounds__(512, 2) void conv2_mfma_kernel(
    const unsigned short* __restrict__ w2f,   // [64][4][12][4][64][8]
    const unsigned short* __restrict__ h1b,   // [64][2048][128]
    const float* __restrict__ b2,             // [256][256]
    unsigned* __restrict__ cnnmax,            // [2048][256] f32-as-u32, relu'd
    int s0)
{
    __shared__ unsigned short Hs[130 * 136];
    const int tid = threadIdx.x;
    const int lane = tid & 63;
    const int wv = __builtin_amdgcn_readfirstlane((int)(tid >> 6));
    const int wm = wv & 3, wn = wv >> 2;
    const int s_l = blockIdx.x;              // 0..63
    const int nt = blockIdx.y;               // 0..15
    const int s = s0 + s_l;
    const int m0 = nt * 128;
    const int bglob = m0 >> 8;
    const int l0 = m0 & 255;
    const int lr = lane & 15;
    const int quad = lane >> 4;
    const int qk = quad * 8;

    // stage B: 130 rows (l0-1 .. l0+128) x 128 ci (VGPR-mediated, predicated)
    const unsigned short* hbase = h1b + ((size_t)(s_l * 2048 + bglob * 256)) * 128;
    for (int idx = tid; idx < 2080; idx += 512) {
        const int rl = idx >> 4;
        const int ci8 = (idx & 15) * 8;
        const int srcl = l0 + rl - 1;
        bf16x8 v = {};
        if (srcl >= 0 && srcl < 256)
            v = *(const bf16x8*)(hbase + (size_t)srcl * 128 + ci8);
        *(bf16x8*)(&Hs[rl * 136 + ci8]) = v;
    }

    // prefetch A chunks 0..5 (24 contiguous 1KB loads) — overlaps B-staging wait
    const unsigned short* Af = w2f + ((size_t)(s_l * 4 + wm) * 48) * 512 + lane * 8;
    bf16x8 af[6][4];
#pragma unroll
    for (int p = 0; p < 6; p++)
#pragma unroll
        for (int r = 0; r < 4; r++)
            af[p][r] = *(const bf16x8*)(Af + (size_t)((p * 4 + r) * 512));
    __syncthreads();

    floatx4 acc[4][4];
#pragma unroll
    for (int r = 0; r < 4; r++)
#pragma unroll
        for (int c = 0; c < 4; c++) acc[r][c] = (floatx4){0.f, 0.f, 0.f, 0.f};

    const int nb = wn * 64;
#pragma unroll
    for (int kc = 0; kc < 12; kc++) {
        const int slot = (kc < 6) ? kc : (kc - 6);
        bf16x8 aa[4];
#pragma unroll
        for (int r = 0; r < 4; r++) aa[r] = af[slot][r];
        if (kc < 6) {
#pragma unroll
            for (int r = 0; r < 4; r++)
                af[slot][r] = *(const bf16x8*)(Af + (size_t)(((kc + 6) * 4 + r) * 512));
        }
        const int tap = kc >> 2;
        const int ci0 = (kc & 3) * 32;
        bf16x8 bb[4];
#pragma unroll
        for (int c = 0; c < 4; c++) {
            const int rl = nb + c * 16 + lr + tap;
            bb[c] = *(const bf16x8*)(&Hs[rl * 136 + ci0 + qk]);
        }
#pragma unroll
        for (int r = 0; r < 4; r++)
#pragma unroll
            for (int c = 0; c < 4; c++)
                acc[r][c] = __builtin_amdgcn_mfma_f32_16x16x32_bf16(aa[r], bb[c], acc[r][c], 0, 0, 0);
    }

    const int co_base = wm * 64;
    const float* b2s = b2 + s * 256;
    unsigned* cmrow = cnnmax + ((size_t)(bglob * 256 + s)) * 256;
#pragma unroll
    for (int r = 0; r < 4; r++) {
#pragma unroll
        for (int e = 0; e < 4; e++) {
            const int co = co_base + r * 16 + quad * 4 + e;
            const float bias = b2s[co];
            float mv = 0.f;
#pragma unroll
            for (int c = 0; c < 4; c++) mv = fmaxf(mv, acc[r][c][e] + bias);
            mv = fmaxf(mv, __shfl_xor(mv, 1));
            mv = fmaxf(mv, __shfl_xor(mv, 2));
            mv = fmaxf(mv, __shfl_xor(mv, 4));
            mv = fmaxf(mv, __shfl_xor(mv, 8));
            if (lr == 0) atomicMax(&cmrow[co], __float_as_uint(mv));
        }
    }
}

// LayerNorm (no affine) from cnnmax -> feat(h); fused sum-of-squares -> sqv
__global__ __launch_bounds__(256) void ln0_kernel(
    const unsigned* __restrict__ cm, float* __restrict__ out, float* __restrict__ sqv)
{
    const int tid = threadIdx.x, lane = tid & 63, wid = tid >> 6;
    const int row = blockIdx.x * 4 + wid;
    const unsigned* xr = cm + (size_t)row * 256;
    float v[4];
#pragma unroll
    for (int i = 0; i < 4; i++) v[i] = __uint_as_float(xr[lane + 64 * i]);
    float sm = wave_sum(v[0] + v[1] + v[2] + v[3]);
    const float mean = sm * (1.f / 256.f);
    float qv = 0.f;
#pragma unroll
    for (int i = 0; i < 4; i++) { const float d = v[i] - mean; qv = fmaf(d, d, qv); }
    qv = wave_sum(qv);
    const float inv = rsqrtf(qv * (1.f / 256.f) + 1e-5f);
    float* orow = out + (size_t)row * 256;
#pragma unroll
    for (int i = 0; i < 4; i++) orow[lane + 64 * i] = (v[i] - mean) * inv;
    if (lane == 0) sqv[row] = qv * inv * inv;
}

// pairwise distances for one (b, 32-i-tile, 16-j-tile); global max via atomic
__global__ __launch_bounds__(256) void dist_kernel(
    const float* __restrict__ feat, const float* __restrict__ sq,
    float* __restrict__ dist, unsigned* __restrict__ dmax)
{
    __shared__ float Fi[32][260];
    __shared__ float Fj[16][260];
    __shared__ float redm[4];
    const int tid = threadIdx.x;
    const int bid = blockIdx.x;
    const int b = bid >> 7, it = (bid >> 4) & 7, jt = bid & 15;
    const float* fb = feat + (size_t)b * 65536;
    for (int idx = tid; idx < 32 * 256; idx += 256) {
        const int r = idx >> 8, e = idx & 255;
        Fi[r][e] = fb[(it * 32 + r) * 256 + e];
    }
    for (int idx = tid; idx < 16 * 256; idx += 256) {
        const int r = idx >> 8, e = idx & 255;
        Fj[r][e] = fb[(jt * 16 + r) * 256 + e];
    }
    __syncthreads();
    const int ii = tid >> 3, j0 = (tid & 7) * 2;
    float acc[2] = {0.f, 0.f};
    for (int e = 0; e < 256; e += 4) {
        const float4 a = *(const float4*)&Fi[ii][e];
#pragma unroll
        for (int u = 0; u < 2; u++) {
            const float4 bv = *(const float4*)&Fj[j0 + u][e];
            acc[u] += a.x * bv.x + a.y * bv.y + a.z * bv.z + a.w * bv.w;
        }
    }
    const float sqi = sq[b * 256 + it * 32 + ii];
    float mymax = 0.f;
#pragma unroll
    for (int u = 0; u < 2; u++) {
        const float d2 = sqi + sq[b * 256 + jt * 16 + j0 + u] - 2.f * acc[u];
        const float d = sqrtf(fmaxf(d2, 0.f));
        dist[((size_t)b * 256 + it * 32 + ii) * 256 + jt * 16 + j0 + u] = d;
        mymax = fmaxf(mymax, d);
    }
    mymax = wave_max(mymax);
    if ((tid & 63) == 0) redm[tid >> 6] = mymax;
    __syncthreads();
    if (tid == 0) {
        const float m = fmaxf(fmaxf(redm[0], redm[1]), fmaxf(redm[2], redm[3]));
        atomicMax(dmax, __float_as_uint(m));
    }
}

// Transpose all transformer weights to bf16 Wt[n][k]. grid (16,16,12): z = layer*6 + id
__global__ __launch_bounds__(256) void prep_wt_kernel(
    const float* __restrict__ wq, const float* __restrict__ wk, const float* __restrict__ wv,
    const float* __restrict__ wo, const float* __restrict__ f1, const float* __restrict__ f2,
    unsigned short* __restrict__ wtb)
{
    __shared__ float t[32][33];
    const int z = blockIdx.z;
    const int l = z / 6, id = z % 6;
    const float* src; int K_, N_; size_t doff;
    switch (id) {
        case 0:  src = wq + (size_t)l * 65536;  K_ = 256; N_ = 256; doff = 0;      break;
        case 1:  src = wk + (size_t)l * 65536;  K_ = 256; N_ = 256; doff = 65536;  break;
        case 2:  src = wv + (size_t)l * 65536;  K_ = 256; N_ = 256; doff = 131072; break;
        case 3:  src = wo + (size_t)l * 65536;  K_ = 256; N_ = 256; doff = 196608; break;
        case 4:  src = f1 + (size_t)l * 131072; K_ = 256; N_ = 512; doff = 262144; break;
        default: src = f2 + (size_t)l * 131072; K_ = 512; N_ = 256; doff = 393216; break;
    }
    const int k0 = blockIdx.x * 32, n0 = blockIdx.y * 32;
    if (k0 >= K_ || n0 >= N_) return;
    unsigned short* dst = wtb + (size_t)l * 524288 + doff;
    const int c = threadIdx.x & 31, rq = threadIdx.x >> 5;
#pragma unroll
    for (int i = 0; i < 4; i++) {
        const int r = rq + i * 8;
        t[r][c] = src[(size_t)(k0 + r) * N_ + n0 + c];
    }
    __syncthreads();
#pragma unroll
    for (int i = 0; i < 4; i++) {
        const int r = rq + i * 8;
        dst[(size_t)(n0 + r) * K_ + k0 + c] = f2bf(t[c][r]);
    }
}

// Fused LayerNorm + bf16 MFMA GEMM. A = fp32 h rows, LN'd in-reg (K=256).
// block 128 (2 waves), wave tile 64m x 32n; grid (16, N/32).
// mode 0: QKV (N=768): n<256 -> o0=q_bf, <512 -> o1=k_bf, else o2=vt_bf ([b,h,d,j])
// mode 2: relu bf16 out o0 (stride 512), N=512 (FFN1)
__global__ __launch_bounds__(128, 2) void lngemm_mfma_kernel(
    const float* __restrict__ Af, const unsigned short* __restrict__ Wt,
    const float* __restrict__ g, const float* __restrict__ bta,
    const float* __restrict__ b0, const float* __restrict__ b1, const float* __restrict__ b2,
    unsigned short* __restrict__ o0, unsigned short* __restrict__ o1, unsigned short* __restrict__ o2,
    int mode)
{
    __shared__ float gs[256], bs_[256];
    const int tid = threadIdx.x;
    const int lane = tid & 63, lr = lane & 15, quad = lane >> 4;
    const int wv = __builtin_amdgcn_readfirstlane((int)(tid >> 6));
    const int m0 = blockIdx.x * 128 + wv * 64;
    const int n0 = blockIdx.y * 32;
    for (int i = tid; i < 256; i += 128) { gs[i] = g[i]; bs_[i] = bta[i]; }
    __syncthreads();

    bf16x8 an[4][8];
#pragma unroll
    for (int r = 0; r < 4; r++) {
        const int row = m0 + r * 16 + lr;
        const float* hr = Af + (size_t)row * 256 + quad * 8;
        float v[8][8];
        float sm = 0.f;
#pragma unroll
        for (int ks = 0; ks < 8; ks++) {
            const floatx4 p0 = *(const floatx4*)(hr + ks * 32);
            const floatx4 p1 = *(const floatx4*)(hr + ks * 32 + 4);
#pragma unroll
            for (int j = 0; j < 4; j++) { v[ks][j] = p0[j]; v[ks][4 + j] = p1[j]; }
#pragma unroll
            for (int j = 0; j < 8; j++) sm += v[ks][j];
        }
        sm += __shfl_xor(sm, 16); sm += __shfl_xor(sm, 32);
        const float mean = sm * (1.f / 256.f);
        float qv = 0.f;
#pragma unroll
        for (int ks = 0; ks < 8; ks++)
#pragma unroll
            for (int j = 0; j < 8; j++) { const float d = v[ks][j] - mean; qv = fmaf(d, d, qv); }
        qv += __shfl_xor(qv, 16); qv += __shfl_xor(qv, 32);
        const float inv = rsqrtf(qv * (1.f / 256.f) + 1e-5f);
#pragma unroll
        for (int ks = 0; ks < 8; ks++) {
            const int e0 = ks * 32 + quad * 8;
            unsigned short tmp[8];
#pragma unroll
            for (int j = 0; j < 8; j++)
                tmp[j] = f2bf((v[ks][j] - mean) * inv * gs[e0 + j] + bs_[e0 + j]);
            an[r][ks] = *(bf16x8*)tmp;
        }
    }

    floatx4 acc[4][2];
#pragma unroll
    for (int r = 0; r < 4; r++)
#pragma unroll
        for (int c = 0; c < 2; c++) acc[r][c] = (floatx4){0.f, 0.f, 0.f, 0.f};

    const unsigned short* Bp = Wt + (size_t)(n0 + lr) * 256 + quad * 8;
#pragma unroll
    for (int ks = 0; ks < 8; ks++) {
        bf16x8 b[2];
#pragma unroll
        for (int c = 0; c < 2; c++) b[c] = *(const bf16x8*)(Bp + (size_t)c * 16 * 256 + ks * 32);
#pragma unroll
        for (int r = 0; r < 4; r++)
#pragma unroll
            for (int c = 0; c < 2; c++)
                acc[r][c] = __builtin_amdgcn_mfma_f32_16x16x32_bf16(an[r][ks], b[c], acc[r][c], 0, 0, 0);
    }

    if (mode == 0) {
        const int which = n0 >> 8, nn0 = n0 & 255;
        if (which < 2) {
            unsigned short* op = which ? o1 : o0;
            const float* bp = which ? b1 : b0;
#pragma unroll
            for (int r = 0; r < 4; r++)
#pragma unroll
                for (int c = 0; c < 2; c++)
#pragma unroll
                    for (int e = 0; e < 4; e++) {
                        const int m = m0 + r * 16 + quad * 4 + e;
                        const int n = nn0 + c * 16 + lr;
                        op[(size_t)m * 256 + n] = f2bf(acc[r][c][e] + bp[n]);
                    }
        } else {
#pragma unroll
            for (int r = 0; r < 4; r++)
#pragma unroll
                for (int c = 0; c < 2; c++)
#pragma unroll
                    for (int e = 0; e < 4; e++) {
                        const int m = m0 + r * 16 + quad * 4 + e;
                        const int nn = nn0 + c * 16 + lr;
                        const int bb_ = m >> 8, j = m & 255, hh = nn >> 5, d = nn & 31;
                        o2[(size_t)((bb_ * 8 + hh) * 32 + d) * 256 + j] = f2bf(acc[r][c][e] + b2[nn]);
                    }
        }
    } else {
#pragma unroll
        for (int r = 0; r < 4; r++)
#pragma unroll
            for (int c = 0; c < 2; c++)
#pragma unroll
                for (int e = 0; e < 4; e++) {
                    const int m = m0 + r * 16 + quad * 4 + e;
                    const int n = n0 + c * 16 + lr;
                    o0[(size_t)m * 512 + n] = f2bf(fmaxf(acc[r][c][e] + b0[n], 0.f));
                }
    }
}

// bf16 MFMA GEMM (bf16 A): C = A @ Wt^T + b0 + R -> fp32 outf (O-proj, FFN2)
// block 128 (2 waves), wave tile 64m x 32n; grid (16, N/32).
__global__ __launch_bounds__(128) void gemm_mfma_kernel(
    const unsigned short* __restrict__ A, const unsigned short* __restrict__ Wt,
    const float* __restrict__ b0, const float* __restrict__ R, float* __restrict__ outf,
    int K)
{
    const int tid = threadIdx.x;
    const int lane = tid & 63, lr = lane & 15, quad = lane >> 4;
    const int wv = __builtin_amdgcn_readfirstlane((int)(tid >> 6));
    const int m0 = blockIdx.x * 128 + wv * 64;
    const int n0 = blockIdx.y * 32;

    floatx4 acc[4][2];
#pragma unroll
    for (int r = 0; r < 4; r++)
#pragma unroll
        for (int c = 0; c < 2; c++) acc[r][c] = (floatx4){0.f, 0.f, 0.f, 0.f};

    const unsigned short* Ap = A + (size_t)(m0 + lr) * K + quad * 8;
    const unsigned short* Bp = Wt + (size_t)(n0 + lr) * K + quad * 8;
    const int nks = K >> 5;
#pragma unroll 4
    for (int ks = 0; ks < nks; ks++) {
        const int ko = ks * 32;
        bf16x8 a[4], b[2];
#pragma unroll
        for (int r = 0; r < 4; r++) a[r] = *(const bf16x8*)(Ap + (size_t)r * 16 * K + ko);
#pragma unroll
        for (int c = 0; c < 2; c++) b[c] = *(const bf16x8*)(Bp + (size_t)c * 16 * K + ko);
#pragma unroll
        for (int r = 0; r < 4; r++)
#pragma unroll
            for (int c = 0; c < 2; c++)
                acc[r][c] = __builtin_amdgcn_mfma_f32_16x16x32_bf16(a[r], b[c], acc[r][c], 0, 0, 0);
    }

#pragma unroll
    for (int r = 0; r < 4; r++)
#pragma unroll
        for (int c = 0; c < 2; c++)
#pragma unroll
            for (int e = 0; e < 4; e++) {
                const int m = m0 + r * 16 + quad * 4 + e;
                const int n = n0 + c * 16 + lr;
                outf[(size_t)m * 256 + n] = acc[r][c][e] + b0[n] + R[(size_t)m * 256 + n];
            }
}

// MFMA attention: grid (4 ic, 8 h, 8 b), block 256 (4 waves, wave = one 16-i tile)
__global__ __launch_bounds__(256) void attn_mfma_kernel(
    const unsigned short* __restrict__ q_bf, const unsigned short* __restrict__ k_bf,
    const unsigned short* __restrict__ vt_bf,
    const float* __restrict__ dist, const unsigned* __restrict__ dmax,
    const float* __restrict__ bw, const float* __restrict__ bb,
    unsigned short* __restrict__ ao_bf)
{
    __shared__ unsigned short Ps[4][16][264];
    const int tid = threadIdx.x;
    const int lane = tid & 63, lr = lane & 15, quad = lane >> 4;
    const int wv = __builtin_amdgcn_readfirstlane((int)(tid >> 6));
    const int ic = blockIdx.x, hh = blockIdx.y, b = blockIdx.z;
    const int i0 = ic * 64 + wv * 16;

    const float dinv = 1.f / (__uint_as_float(*dmax) + 1e-6f);
    const float w0 = bw[0 * 8 + hh], w1 = bw[1 * 8 + hh], w2 = bw[2 * 8 + hh], w3 = bw[3 * 8 + hh];
    const float bbh = bb[hh];
    const float scale = 0.17677669529663687f;

    const bf16x8 aq = *(const bf16x8*)(q_bf + (size_t)(b * 256 + i0 + lr) * 256 + hh * 32 + quad * 8);
    floatx4 sc[16];
#pragma unroll
    for (int c = 0; c < 16; c++) {
        const bf16x8 bk = *(const bf16x8*)(k_bf + (size_t)(b * 256 + c * 16 + lr) * 256 + hh * 32 + quad * 8);
        sc[c] = __builtin_amdgcn_mfma_f32_16x16x32_bf16(aq, bk, (floatx4){0.f, 0.f, 0.f, 0.f}, 0, 0, 0);
    }

#pragma unroll
    for (int e = 0; e < 4; e++) {
        const int i = i0 + quad * 4 + e;
        const float* drow = dist + ((size_t)(b * 256 + i)) * 256;
        float bs[16];
        float mx = -1e30f;
#pragma unroll
        for (int c = 0; c < 16; c++) {
            const int j = c * 16 + lr;
            const float dn = drow[j] * dinv;
            const float rd = fabsf((float)(i - j)) * (1.f / 255.f);
            bs[c] = sc[c][e] * scale + w0 * dn + w1 * rd + w2 * (1.f - rd) + w3 * (1.f - dn) + bbh;
            mx = fmaxf(mx, bs[c]);
        }
        mx = fmaxf(mx, __shfl_xor(mx, 1)); mx = fmaxf(mx, __shfl_xor(mx, 2));
        mx = fmaxf(mx, __shfl_xor(mx, 4)); mx = fmaxf(mx, __shfl_xor(mx, 8));
        float sm = 0.f;
#pragma unroll
        for (int c = 0; c < 16; c++) { bs[c] = __expf(bs[c] - mx); sm += bs[c]; }
        sm += __shfl_xor(sm, 1); sm += __shfl_xor(sm, 2);
        sm += __shfl_xor(sm, 4); sm += __shfl_xor(sm, 8);
        const float rs = 1.f / sm;
#pragma unroll
        for (int c = 0; c < 16; c++)
            Ps[wv][quad * 4 + e][c * 16 + lr] = f2bf(bs[c] * rs);
    }
    __syncthreads();

    floatx4 oc[2];
    oc[0] = (floatx4){0.f, 0.f, 0.f, 0.f};
    oc[1] = (floatx4){0.f, 0.f, 0.f, 0.f};
    const unsigned short* vtb = vt_bf + (size_t)(b * 8 + hh) * 8192;
#pragma unroll
    for (int ks = 0; ks < 8; ks++) {
        const bf16x8 ap = *(const bf16x8*)(&Ps[wv][lr][ks * 32 + quad * 8]);
#pragma unroll
        for (int c2 = 0; c2 < 2; c2++) {
            const bf16x8 bvv = *(const bf16x8*)(vtb + (size_t)(c2 * 16 + lr) * 256 + ks * 32 + quad * 8);
            oc[c2] = __builtin_amdgcn_mfma_f32_16x16x32_bf16(ap, bvv, oc[c2], 0, 0, 0);
        }
    }
#pragma unroll
    for (int c2 = 0; c2 < 2; c2++)
#pragma unroll
        for (int e = 0; e < 4; e++)
            ao_bf[(size_t)(b * 256 + i0 + quad * 4 + e) * 256 + hh * 32 + c2 * 16 + lr] = f2bf(oc[c2][e]);
}

// chunked max-pool over segments + final FC [2048 -> 2]
__global__ __launch_bounds__(256) void pool_fc_kernel(
    const float* __restrict__ h, const float* __restrict__ fcw,
    const float* __restrict__ fcb, float* __restrict__ out)
{
    __shared__ float red[8];
    const int b = blockIdx.x, tid = threadIdx.x, lane = tid & 63, wid = tid >> 6;
    float a0 = 0.f, a1 = 0.f;
    for (int ns = 0; ns < 8; ns++) {
        const float* hp = h + ((size_t)(b * 256 + ns * 32)) * 256 + tid;
        float m = hp[0];
#pragma unroll
        for (int r = 1; r < 32; r++) m = fmaxf(m, hp[(size_t)r * 256]);
        a0 = fmaf(m, fcw[(ns * 256 + tid) * 2 + 0], a0);
        a1 = fmaf(m, fcw[(ns * 256 + tid) * 2 + 1], a1);
    }
    a0 = wave_sum(a0);
    a1 = wave_sum(a1);
    if (lane == 0) { red[wid] = a0; red[4 + wid] = a1; }
    __syncthreads();
    if (tid == 0) out[b * 2 + 0] = red[0] + red[1] + red[2] + red[3] + fcb[0];
    if (tid == 1) out[b * 2 + 1] = red[4] + red[5] + red[6] + red[7] + fcb[1];
}

extern "C" void kernel_launch(void* const* d_in, const int* in_sizes, int n_in,
                              void* d_out, int out_size, void* d_ws, size_t ws_size,
                              hipStream_t stream)
{
    (void)in_sizes; (void)n_in; (void)out_size; (void)ws_size;
    const float* x       = (const float*)d_in[0];
    const float* conv1_w = (const float*)d_in[1];
    const float* conv1_b = (const float*)d_in[2];
    const float* conv2_w = (const float*)d_in[3];
    const float* conv2_b = (const float*)d_in[4];
    const float* ln1_g   = (const float*)d_in[5];
    const float* ln1_b   = (const float*)d_in[6];
    const float* wq = (const float*)d_in[7];  const float* bq = (const float*)d_in[8];
    const float* wk = (const float*)d_in[9];  const float* bk = (const float*)d_in[10];
    const float* wvp = (const float*)d_in[11]; const float* bv = (const float*)d_in[12];
    const float* wo = (const float*)d_in[13]; const float* bo = (const float*)d_in[14];
    const float* bias_w = (const float*)d_in[15];
    const float* bias_b = (const float*)d_in[16];
    const float* ln2_g  = (const float*)d_in[17];
    const float* ln2_b  = (const float*)d_in[18];
    const float* ffn_w1 = (const float*)d_in[19]; const float* ffn_b1 = (const float*)d_in[20];
    const float* ffn_w2 = (const float*)d_in[21]; const float* ffn_b2 = (const float*)d_in[22];
    const float* fc_w   = (const float*)d_in[23]; const float* fc_b = (const float*)d_in[24];
    float* out = (float*)d_out;

    float* ws = (float*)d_ws;
    float* h    = ws;                         // [2048,256] fp32
    float* dist = h + 524288;                 // [8,256,256] fp32
    float* sqv  = dist + 524288;              // [2048]
    unsigned* dmax = (unsigned*)(sqv + 2048);
    unsigned* cnnmax = (unsigned*)(sqv + 2048 + 16);              // [2048,256]
    unsigned short* hn_bf = (unsigned short*)(sqv + 2048 + 16 + 524288);  // (spare)
    unsigned short* q_bf  = hn_bf + 524288;
    unsigned short* k_bf  = q_bf + 524288;
    unsigned short* vt_bf = k_bf + 524288;    // [8,8,32,256] = [b,h,d,j]
    unsigned short* ao_bf = vt_bf + 524288;   // [2048,256]
    unsigned short* fm_bf = ao_bf + 524288;   // [2048,512]
    unsigned short* wtb   = fm_bf + 1048576;  // [2][524288]
    unsigned short* w2f   = wtb + 1048576;    // 64*98304
    unsigned short* h1b   = w2f + 6291456;    // 64*2048*128

    init_kernel<<<2048, 256, 0, stream>>>(dmax, cnnmax);
    prep_wt_kernel<<<dim3(16, 16, 12), 256, 0, stream>>>(wq, wk, wvp, wo, ffn_w1, ffn_w2, wtb);
    for (int g = 0; g < 4; g++) {
        const int s0 = g * 64;
        prep_w2_kernel<<<dim3(64, 8), 256, 0, stream>>>(conv2_w, w2f, s0);
        conv1_kernel<<<dim3(64, 8), 256, 0, stream>>>(x, conv1_w, conv1_b, h1b, s0);
        conv2_mfma_kernel<<<dim3(64, 16), 512, 0, stream>>>(w2f, h1b, conv2_b, cnnmax, s0);
    }
    ln0_kernel<<<512, 256, 0, stream>>>(cnnmax, h, sqv);
    dist_kernel<<<1024, 256, 0, stream>>>(h, sqv, dist, dmax);

    for (int l = 0; l < 2; l++) {
        const unsigned short* wqkvT = wtb + (size_t)l * 524288;
        const unsigned short* woT   = wqkvT + 196608;
        const unsigned short* f1T   = wqkvT + 262144;
        const unsigned short* f2T   = wqkvT + 393216;

        lngemm_mfma_kernel<<<dim3(16, 24), 128, 0, stream>>>(
            h, wqkvT, ln1_g + l * 256, ln1_b + l * 256,
            bq + l * 256, bk + l * 256, bv + l * 256,
            q_bf, k_bf, vt_bf, 0);
        attn_mfma_kernel<<<dim3(4, 8, 8), 256, 0, stream>>>(
            q_bf, k_bf, vt_bf, dist, dmax, bias_w + l * 32, bias_b + l * 8, ao_bf);
        gemm_mfma_kernel<<<dim3(16, 8), 128, 0, stream>>>(
            ao_bf, woT, bo + l * 256, h, h, 256);
        lngemm_mfma_kernel<<<dim3(16, 16), 128, 0, stream>>>(
            h, f1T, ln2_g + l * 256, ln2_b + l * 256,
            ffn_b1 + l * 512, nullptr, nullptr,
            fm_bf, nullptr, nullptr, 2);
        gemm_mfma_kernel<<<dim3(16, 8), 128, 0, stream>>>(
            fm_bf, f2T, ffn_b2 + l * 256, h, h, 512);
    }
    pool_fc_kernel<<<8, 256, 0, stream>>>(h, fc_w, fc_b, out);
}

// Round 8
// 612.057 us; speedup vs baseline: 1.2950x; 1.2950x over previous
//
#include <hip/hip_runtime.h>
#include <hip/hip_bf16.h>

// Model dims: B=8, S=256, C=4, L=256, E=256, H=8, DH=32, NL=2, NS=8

typedef float floatx4 __attribute__((ext_vector_type(4)));
typedef short bf16x8 __attribute__((ext_vector_type(8)));

__device__ __forceinline__ float wave_sum(float v) {
    v += __shfl_xor(v, 32); v += __shfl_xor(v, 16); v += __shfl_xor(v, 8);
    v += __shfl_xor(v, 4);  v += __shfl_xor(v, 2);  v += __shfl_xor(v, 1);
    return v;
}
__device__ __forceinline__ float wave_max(float v) {
    v = fmaxf(v, __shfl_xor(v, 32)); v = fmaxf(v, __shfl_xor(v, 16));
    v = fmaxf(v, __shfl_xor(v, 8));  v = fmaxf(v, __shfl_xor(v, 4));
    v = fmaxf(v, __shfl_xor(v, 2));  v = fmaxf(v, __shfl_xor(v, 1));
    return v;
}
__device__ __forceinline__ unsigned short f2bf(float v) {
    unsigned b = __float_as_uint(v);
    unsigned r = (b + 0x7fffu + ((b >> 16) & 1u)) >> 16;
    return (unsigned short)r;
}

__global__ void init_kernel(unsigned* dmax, unsigned* cnnmax) {
    const size_t i = (size_t)blockIdx.x * 256 + threadIdx.x;
    cnnmax[i] = 0u;
    if (i == 0) *dmax = 0u;
}

// w2 [S][256co][128ci][3tap] fp32 -> w2b [256 s][256co][384 kk=tap*128+ci] bf16
// ALL segments in one dispatch. grid (256 s, 4 part), 256 thr.
__global__ __launch_bounds__(256) void prep_w2_kernel(
    const float* __restrict__ w2, unsigned short* __restrict__ w2b)
{
    const int s = blockIdx.x;
    const int part = blockIdx.y;
    const float* src = w2 + (size_t)s * 98304;
    unsigned short* dst = w2b + (size_t)s * 98304;
    for (int o = part * 24576 + threadIdx.x; o < (part + 1) * 24576; o += 256) {
        const int kk = o % 384, co = o / 384;
        const int ci = kk & 127, tap = kk >> 7;
        dst[o] = f2bf(src[(size_t)co * 384 + ci * 3 + tap]);
    }
}

// Fused conv1+conv2 implicit GEMM. One dispatch, grid (s=256, nt=16), 512 thr.
// Phase 1: conv1 for this block's 130 L-rows (l0-1..l0+128) computed in-LDS
//          from x[b,s] (4KB) + w1[s] (6KB) -> Hs bf16 padded tile.
// Phase 2: r6's proven MFMA body: A (w2b) direct from global, B from Hs.
// XCD swizzle: linear id = s + 256*nt => id%8 == s%8 -> all 16 m-tiles of a
// segment on one XCD; w2b slice fetched ~once per XCD.
__global__ __launch_bounds__(512) void conv2_fused_kernel(
    const unsigned short* __restrict__ w2b,   // [256][256][384]
    const float* __restrict__ x,              // [8][256][4][256]
    const float* __restrict__ w1,             // [256][128][12]
    const float* __restrict__ b1,             // [256][128]
    const float* __restrict__ b2,             // [256][256]
    unsigned* __restrict__ cnnmax)            // [2048][256] f32-as-u32, relu'd
{
    __shared__ float xs[4][258];
    __shared__ float w1s[1536];
    __shared__ unsigned short Hs[130 * 136];
    const int tid = threadIdx.x;
    const int lane = tid & 63;
    const int wv = __builtin_amdgcn_readfirstlane((int)(tid >> 6));
    const int wm = wv & 3, wn = wv >> 2;
    const int s = blockIdx.x;                // 0..255
    const int nt = blockIdx.y;               // 0..15
    const int b = nt >> 1;
    const int l0 = (nt & 1) * 128;
    const int lr = lane & 15;
    const int quad = lane >> 4;
    const int qk = quad * 8;

    // ---- stage x slice + w1 slice ----
    const float* xp = x + ((size_t)(b * 256 + s)) * 1024;
    for (int i = tid; i < 1024; i += 512) {
        const int ci = i >> 8, l = i & 255;
        xs[ci][l + 1] = xp[i];
    }
    if (tid < 4) { xs[tid][0] = 0.f; xs[tid][257] = 0.f; }
    const float* w1p = w1 + (size_t)s * 1536;
    for (int i = tid; i < 1536; i += 512) w1s[i] = w1p[i];
    __syncthreads();

    // ---- conv1 phase: 130 rows x 128 co ----
    {
        const int co = tid & 127;
        const int g = tid >> 7;              // 0..3
        float wreg[12];
#pragma unroll
        for (int k = 0; k < 12; k++) wreg[k] = w1s[co * 12 + k];
        const float bb1 = b1[s * 128 + co];
        for (int pr = g; pr < 130; pr += 4) {
            const int l = l0 - 1 + pr;
            float a = 0.f;
            if ((unsigned)l < 256u) {
                a = bb1;
#pragma unroll
                for (int ci = 0; ci < 4; ci++)
#pragma unroll
                    for (int k = 0; k < 3; k++) a = fmaf(wreg[ci * 3 + k], xs[ci][l + k], a);
                a = fmaxf(a, 0.f);
            }
            Hs[pr * 136 + co] = f2bf(a);
        }
    }
    __syncthreads();

    // ---- conv2 MFMA phase (r6 body) ----
    floatx4 acc[4][4];
#pragma unroll
    for (int r = 0; r < 4; r++)
#pragma unroll
        for (int c = 0; c < 4; c++) acc[r][c] = (floatx4){0.f, 0.f, 0.f, 0.f};

    const int co_base = wm * 64;
    const unsigned short* wp = w2b + ((size_t)(s * 256 + co_base + lr)) * 384 + qk;
    const int nb = wn * 64;

#pragma unroll
    for (int tap = 0; tap < 3; tap++) {
#pragma unroll
        for (int ci0 = 0; ci0 < 128; ci0 += 32) {
            const int kk0 = tap * 128 + ci0;
            bf16x8 a[4], bb[4];
#pragma unroll
            for (int r = 0; r < 4; r++)
                a[r] = *(const bf16x8*)(wp + r * (16 * 384) + kk0);
#pragma unroll
            for (int c = 0; c < 4; c++) {
                const int rl = nb + c * 16 + lr + tap;
                bb[c] = *(const bf16x8*)(&Hs[rl * 136 + ci0 + qk]);
            }
#pragma unroll
            for (int r = 0; r < 4; r++)
#pragma unroll
                for (int c = 0; c < 4; c++)
                    acc[r][c] = __builtin_amdgcn_mfma_f32_16x16x32_bf16(a[r], bb[c], acc[r][c], 0, 0, 0);
        }
    }

    const float* b2s = b2 + s * 256;
    unsigned* cmrow = cnnmax + ((size_t)(b * 256 + s)) * 256;
#pragma unroll
    for (int r = 0; r < 4; r++) {
#pragma unroll
        for (int e = 0; e < 4; e++) {
            const int co = co_base + r * 16 + quad * 4 + e;
            const float bias = b2s[co];
            float mv = 0.f;
#pragma unroll
            for (int c = 0; c < 4; c++) mv = fmaxf(mv, acc[r][c][e] + bias);
            mv = fmaxf(mv, __shfl_xor(mv, 1));
            mv = fmaxf(mv, __shfl_xor(mv, 2));
            mv = fmaxf(mv, __shfl_xor(mv, 4));
            mv = fmaxf(mv, __shfl_xor(mv, 8));
            if (lr == 0) atomicMax(&cmrow[co], __float_as_uint(mv));
        }
    }
}

// LayerNorm (no affine) from cnnmax -> feat(h); fused sum-of-squares -> sqv
__global__ __launch_bounds__(256) void ln0_kernel(
    const unsigned* __restrict__ cm, float* __restrict__ out, float* __restrict__ sqv)
{
    const int tid = threadIdx.x, lane = tid & 63, wid = tid >> 6;
    const int row = blockIdx.x * 4 + wid;
    const unsigned* xr = cm + (size_t)row * 256;
    float v[4];
#pragma unroll
    for (int i = 0; i < 4; i++) v[i] = __uint_as_float(xr[lane + 64 * i]);
    float sm = wave_sum(v[0] + v[1] + v[2] + v[3]);
    const float mean = sm * (1.f / 256.f);
    float qv = 0.f;
#pragma unroll
    for (int i = 0; i < 4; i++) { const float d = v[i] - mean; qv = fmaf(d, d, qv); }
    qv = wave_sum(qv);
    const float inv = rsqrtf(qv * (1.f / 256.f) + 1e-5f);
    float* orow = out + (size_t)row * 256;
#pragma unroll
    for (int i = 0; i < 4; i++) orow[lane + 64 * i] = (v[i] - mean) * inv;
    if (lane == 0) sqv[row] = qv * inv * inv;
}

// pairwise distances for one (b, 32-i-tile, 16-j-tile); global max via atomic
__global__ __launch_bounds__(256) void dist_kernel(
    const float* __restrict__ feat, const float* __restrict__ sq,
    float* __restrict__ dist, unsigned* __restrict__ dmax)
{
    __shared__ float Fi[32][260];
    __shared__ float Fj[16][260];
    __shared__ float redm[4];
    const int tid = threadIdx.x;
    const int bid = blockIdx.x;
    const int b = bid >> 7, it = (bid >> 4) & 7, jt = bid & 15;
    const float* fb = feat + (size_t)b * 65536;
    for (int idx = tid; idx < 32 * 256; idx += 256) {
        const int r = idx >> 8, e = idx & 255;
        Fi[r][e] = fb[(it * 32 + r) * 256 + e];
    }
    for (int idx = tid; idx < 16 * 256; idx += 256) {
        const int r = idx >> 8, e = idx & 255;
        Fj[r][e] = fb[(jt * 16 + r) * 256 + e];
    }
    __syncthreads();
    const int ii = tid >> 3, j0 = (tid & 7) * 2;
    float acc[2] = {0.f, 0.f};
    for (int e = 0; e < 256; e += 4) {
        const float4 a = *(const float4*)&Fi[ii][e];
#pragma unroll
        for (int u = 0; u < 2; u++) {
            const float4 bv = *(const float4*)&Fj[j0 + u][e];
            acc[u] += a.x * bv.x + a.y * bv.y + a.z * bv.z + a.w * bv.w;
        }
    }
    const float sqi = sq[b * 256 + it * 32 + ii];
    float mymax = 0.f;
#pragma unroll
    for (int u = 0; u < 2; u++) {
        const float d2 = sqi + sq[b * 256 + jt * 16 + j0 + u] - 2.f * acc[u];
        const float d = sqrtf(fmaxf(d2, 0.f));
        dist[((size_t)b * 256 + it * 32 + ii) * 256 + jt * 16 + j0 + u] = d;
        mymax = fmaxf(mymax, d);
    }
    mymax = wave_max(mymax);
    if ((tid & 63) == 0) redm[tid >> 6] = mymax;
    __syncthreads();
    if (tid == 0) {
        const float m = fmaxf(fmaxf(redm[0], redm[1]), fmaxf(redm[2], redm[3]));
        atomicMax(dmax, __float_as_uint(m));
    }
}

// LayerNorm with affine, fp32 in -> bf16 out
__global__ __launch_bounds__(256) void ln_bf_kernel(
    const float* __restrict__ x, const float* __restrict__ g, const float* __restrict__ bta,
    unsigned short* __restrict__ out)
{
    const int tid = threadIdx.x, lane = tid & 63, wid = tid >> 6;
    const int row = blockIdx.x * 4 + wid;
    const float* xr = x + (size_t)row * 256;
    float v[4];
#pragma unroll
    for (int i = 0; i < 4; i++) v[i] = xr[lane + 64 * i];
    float sm = wave_sum(v[0] + v[1] + v[2] + v[3]);
    const float mean = sm * (1.f / 256.f);
    float q = 0.f;
#pragma unroll
    for (int i = 0; i < 4; i++) { const float d = v[i] - mean; q = fmaf(d, d, q); }
    q = wave_sum(q);
    const float inv = rsqrtf(q * (1.f / 256.f) + 1e-5f);
    unsigned short* orow = out + (size_t)row * 256;
#pragma unroll
    for (int i = 0; i < 4; i++) {
        const int e = lane + 64 * i;
        orow[e] = f2bf((v[i] - mean) * inv * g[e] + bta[e]);
    }
}

// Transpose all transformer weights to bf16 Wt[n][k]. grid (16,16,12): z = layer*6 + id
__global__ __launch_bounds__(256) void prep_wt_kernel(
    const float* __restrict__ wq, const float* __restrict__ wk, const float* __restrict__ wv,
    const float* __restrict__ wo, const float* __restrict__ f1, const float* __restrict__ f2,
    unsigned short* __restrict__ wtb)
{
    __shared__ float t[32][33];
    const int z = blockIdx.z;
    const int l = z / 6, id = z % 6;
    const float* src; int K_, N_; size_t doff;
    switch (id) {
        case 0:  src = wq + (size_t)l * 65536;  K_ = 256; N_ = 256; doff = 0;      break;
        case 1:  src = wk + (size_t)l * 65536;  K_ = 256; N_ = 256; doff = 65536;  break;
        case 2:  src = wv + (size_t)l * 65536;  K_ = 256; N_ = 256; doff = 131072; break;
        case 3:  src = wo + (size_t)l * 65536;  K_ = 256; N_ = 256; doff = 196608; break;
        case 4:  src = f1 + (size_t)l * 131072; K_ = 256; N_ = 512; doff = 262144; break;
        default: src = f2 + (size_t)l * 131072; K_ = 512; N_ = 256; doff = 393216; break;
    }
    const int k0 = blockIdx.x * 32, n0 = blockIdx.y * 32;
    if (k0 >= K_ || n0 >= N_) return;
    unsigned short* dst = wtb + (size_t)l * 524288 + doff;
    const int c = threadIdx.x & 31, rq = threadIdx.x >> 5;
#pragma unroll
    for (int i = 0; i < 4; i++) {
        const int r = rq + i * 8;
        t[r][c] = src[(size_t)(k0 + r) * N_ + n0 + c];
    }
    __syncthreads();
#pragma unroll
    for (int i = 0; i < 4; i++) {
        const int r = rq + i * 8;
        dst[(size_t)(n0 + r) * K_ + k0 + c] = f2bf(t[c][r]);
    }
}

// bf16 MFMA GEMM: C[M=2048][N] = A[M][K] @ Wt[N][K]^T (+bias, mode-dependent epilogue)
// block 128 (2 waves), wave tile 64m x 32n; grid (16, N/32).
__global__ __launch_bounds__(128) void gemm_mfma_kernel(
    const unsigned short* __restrict__ A, const unsigned short* __restrict__ Wt,
    const float* __restrict__ b0, const float* __restrict__ b1, const float* __restrict__ b2,
    const float* __restrict__ R, float* __restrict__ outf,
    unsigned short* __restrict__ o0, unsigned short* __restrict__ o1, unsigned short* __restrict__ o2,
    int K, int mode)
{
    const int tid = threadIdx.x;
    const int lane = tid & 63, lr = lane & 15, quad = lane >> 4;
    const int wv = __builtin_amdgcn_readfirstlane((int)(tid >> 6));
    const int m0 = blockIdx.x * 128 + wv * 64;
    const int n0 = blockIdx.y * 32;

    floatx4 acc[4][2];
#pragma unroll
    for (int r = 0; r < 4; r++)
#pragma unroll
        for (int c = 0; c < 2; c++) acc[r][c] = (floatx4){0.f, 0.f, 0.f, 0.f};

    const unsigned short* Ap = A + (size_t)(m0 + lr) * K + quad * 8;
    const unsigned short* Bp = Wt + (size_t)(n0 + lr) * K + quad * 8;
    const int nks = K >> 5;
#pragma unroll 4
    for (int ks = 0; ks < nks; ks++) {
        const int ko = ks * 32;
        bf16x8 a[4], b[2];
#pragma unroll
        for (int r = 0; r < 4; r++) a[r] = *(const bf16x8*)(Ap + (size_t)r * 16 * K + ko);
#pragma unroll
        for (int c = 0; c < 2; c++) b[c] = *(const bf16x8*)(Bp + (size_t)c * 16 * K + ko);
#pragma unroll
        for (int r = 0; r < 4; r++)
#pragma unroll
            for (int c = 0; c < 2; c++)
                acc[r][c] = __builtin_amdgcn_mfma_f32_16x16x32_bf16(a[r], b[c], acc[r][c], 0, 0, 0);
    }

    if (mode == 0) {
        const int which = n0 >> 8, nn0 = n0 & 255;
        if (which < 2) {
            unsigned short* op = which ? o1 : o0;
            const float* bp = which ? b1 : b0;
#pragma unroll
            for (int r = 0; r < 4; r++)
#pragma unroll
                for (int c = 0; c < 2; c++)
#pragma unroll
                    for (int e = 0; e < 4; e++) {
                        const int m = m0 + r * 16 + quad * 4 + e;
                        const int n = nn0 + c * 16 + lr;
                        op[(size_t)m * 256 + n] = f2bf(acc[r][c][e] + bp[n]);
                    }
        } else {
#pragma unroll
            for (int r = 0; r < 4; r++)
#pragma unroll
                for (int c = 0; c < 2; c++)
#pragma unroll
                    for (int e = 0; e < 4; e++) {
                        const int m = m0 + r * 16 + quad * 4 + e;
                        const int nn = nn0 + c * 16 + lr;
                        const int bb_ = m >> 8, j = m & 255, hh = nn >> 5, d = nn & 31;
                        o2[(size_t)((bb_ * 8 + hh) * 32 + d) * 256 + j] = f2bf(acc[r][c][e] + b2[nn]);
                    }
        }
    } else if (mode == 1) {
#pragma unroll
        for (int r = 0; r < 4; r++)
#pragma unroll
            for (int c = 0; c < 2; c++)
#pragma unroll
                for (int e = 0; e < 4; e++) {
                    const int m = m0 + r * 16 + quad * 4 + e;
                    const int n = n0 + c * 16 + lr;
                    outf[(size_t)m * 256 + n] = acc[r][c][e] + b0[n] + R[(size_t)m * 256 + n];
                }
    } else {
#pragma unroll
        for (int r = 0; r < 4; r++)
#pragma unroll
            for (int c = 0; c < 2; c++)
#pragma unroll
                for (int e = 0; e < 4; e++) {
                    const int m = m0 + r * 16 + quad * 4 + e;
                    const int n = n0 + c * 16 + lr;
                    o0[(size_t)m * 512 + n] = f2bf(fmaxf(acc[r][c][e] + b0[n], 0.f));
                }
    }
}

// MFMA attention: grid (4 ic, 8 h, 8 b), block 256 (4 waves, wave = one 16-i tile)
__global__ __launch_bounds__(256) void attn_mfma_kernel(
    const unsigned short* __restrict__ q_bf, const unsigned short* __restrict__ k_bf,
    const unsigned short* __restrict__ vt_bf,
    const float* __restrict__ dist, const unsigned* __restrict__ dmax,
    const float* __restrict__ bw, const float* __restrict__ bb,
    unsigned short* __restrict__ ao_bf)
{
    __shared__ unsigned short Ps[4][16][264];
    const int tid = threadIdx.x;
    const int lane = tid & 63, lr = lane & 15, quad = lane >> 4;
    const int wv = __builtin_amdgcn_readfirstlane((int)(tid >> 6));
    const int ic = blockIdx.x, hh = blockIdx.y, b = blockIdx.z;
    const int i0 = ic * 64 + wv * 16;

    const float dinv = 1.f / (__uint_as_float(*dmax) + 1e-6f);
    const float w0 = bw[0 * 8 + hh], w1 = bw[1 * 8 + hh], w2 = bw[2 * 8 + hh], w3 = bw[3 * 8 + hh];
    const float bbh = bb[hh];
    const float scale = 0.17677669529663687f;

    const bf16x8 aq = *(const bf16x8*)(q_bf + (size_t)(b * 256 + i0 + lr) * 256 + hh * 32 + quad * 8);
    floatx4 sc[16];
#pragma unroll
    for (int c = 0; c < 16; c++) {
        const bf16x8 bk = *(const bf16x8*)(k_bf + (size_t)(b * 256 + c * 16 + lr) * 256 + hh * 32 + quad * 8);
        sc[c] = __builtin_amdgcn_mfma_f32_16x16x32_bf16(aq, bk, (floatx4){0.f, 0.f, 0.f, 0.f}, 0, 0, 0);
    }

#pragma unroll
    for (int e = 0; e < 4; e++) {
        const int i = i0 + quad * 4 + e;
        const float* drow = dist + ((size_t)(b * 256 + i)) * 256;
        float bs[16];
        float mx = -1e30f;
#pragma unroll
        for (int c = 0; c < 16; c++) {
            const int j = c * 16 + lr;
            const float dn = drow[j] * dinv;
            const float rd = fabsf((float)(i - j)) * (1.f / 255.f);
            bs[c] = sc[c][e] * scale + w0 * dn + w1 * rd + w2 * (1.f - rd) + w3 * (1.f - dn) + bbh;
            mx = fmaxf(mx, bs[c]);
        }
        mx = fmaxf(mx, __shfl_xor(mx, 1)); mx = fmaxf(mx, __shfl_xor(mx, 2));
        mx = fmaxf(mx, __shfl_xor(mx, 4)); mx = fmaxf(mx, __shfl_xor(mx, 8));
        float sm = 0.f;
#pragma unroll
        for (int c = 0; c < 16; c++) { bs[c] = __expf(bs[c] - mx); sm += bs[c]; }
        sm += __shfl_xor(sm, 1); sm += __shfl_xor(sm, 2);
        sm += __shfl_xor(sm, 4); sm += __shfl_xor(sm, 8);
        const float rs = 1.f / sm;
#pragma unroll
        for (int c = 0; c < 16; c++)
            Ps[wv][quad * 4 + e][c * 16 + lr] = f2bf(bs[c] * rs);
    }
    __syncthreads();

    floatx4 oc[2];
    oc[0] = (floatx4){0.f, 0.f, 0.f, 0.f};
    oc[1] = (floatx4){0.f, 0.f, 0.f, 0.f};
    const unsigned short* vtb = vt_bf + (size_t)(b * 8 + hh) * 8192;
#pragma unroll
    for (int ks = 0; ks < 8; ks++) {
        const bf16x8 ap = *(const bf16x8*)(&Ps[wv][lr][ks * 32 + quad * 8]);
#pragma unroll
        for (int c2 = 0; c2 < 2; c2++) {
            const bf16x8 bvv = *(const bf16x8*)(vtb + (size_t)(c2 * 16 + lr) * 256 + ks * 32 + quad * 8);
            oc[c2] = __builtin_amdgcn_mfma_f32_16x16x32_bf16(ap, bvv, oc[c2], 0, 0, 0);
        }
    }
#pragma unroll
    for (int c2 = 0; c2 < 2; c2++)
#pragma unroll
        for (int e = 0; e < 4; e++)
            ao_bf[(size_t)(b * 256 + i0 + quad * 4 + e) * 256 + hh * 32 + c2 * 16 + lr] = f2bf(oc[c2][e]);
}

// chunked max-pool over segments + final FC [2048 -> 2]
__global__ __launch_bounds__(256) void pool_fc_kernel(
    const float* __restrict__ h, const float* __restrict__ fcw,
    const float* __restrict__ fcb, float* __restrict__ out)
{
    __shared__ float red[8];
    const int b = blockIdx.x, tid = threadIdx.x, lane = tid & 63, wid = tid >> 6;
    float a0 = 0.f, a1 = 0.f;
    for (int ns = 0; ns < 8; ns++) {
        const float* hp = h + ((size_t)(b * 256 + ns * 32)) * 256 + tid;
        float m = hp[0];
#pragma unroll
        for (int r = 1; r < 32; r++) m = fmaxf(m, hp[(size_t)r * 256]);
        a0 = fmaf(m, fcw[(ns * 256 + tid) * 2 + 0], a0);
        a1 = fmaf(m, fcw[(ns * 256 + tid) * 2 + 1], a1);
    }
    a0 = wave_sum(a0);
    a1 = wave_sum(a1);
    if (lane == 0) { red[wid] = a0; red[4 + wid] = a1; }
    __syncthreads();
    if (tid == 0) out[b * 2 + 0] = red[0] + red[1] + red[2] + red[3] + fcb[0];
    if (tid == 1) out[b * 2 + 1] = red[4] + red[5] + red[6] + red[7] + fcb[1];
}

extern "C" void kernel_launch(void* const* d_in, const int* in_sizes, int n_in,
                              void* d_out, int out_size, void* d_ws, size_t ws_size,
                              hipStream_t stream)
{
    (void)in_sizes; (void)n_in; (void)out_size; (void)ws_size;
    const float* x       = (const float*)d_in[0];
    const float* conv1_w = (const float*)d_in[1];
    const float* conv1_b = (const float*)d_in[2];
    const float* conv2_w = (const float*)d_in[3];
    const float* conv2_b = (const float*)d_in[4];
    const float* ln1_g   = (const float*)d_in[5];
    const float* ln1_b   = (const float*)d_in[6];
    const float* wq = (const float*)d_in[7];  const float* bq = (const float*)d_in[8];
    const float* wk = (const float*)d_in[9];  const float* bk = (const float*)d_in[10];
    const float* wvp = (const float*)d_in[11]; const float* bv = (const float*)d_in[12];
    const float* wo = (const float*)d_in[13]; const float* bo = (const float*)d_in[14];
    const float* bias_w = (const float*)d_in[15];
    const float* bias_b = (const float*)d_in[16];
    const float* ln2_g  = (const float*)d_in[17];
    const float* ln2_b  = (const float*)d_in[18];
    const float* ffn_w1 = (const float*)d_in[19]; const float* ffn_b1 = (const float*)d_in[20];
    const float* ffn_w2 = (const float*)d_in[21]; const float* ffn_b2 = (const float*)d_in[22];
    const float* fc_w   = (const float*)d_in[23]; const float* fc_b = (const float*)d_in[24];
    float* out = (float*)d_out;

    float* ws = (float*)d_ws;
    float* h    = ws;                         // [2048,256] fp32
    float* dist = h + 524288;                 // [8,256,256] fp32
    float* sqv  = dist + 524288;              // [2048]
    unsigned* dmax = (unsigned*)(sqv + 2048);
    unsigned* cnnmax = (unsigned*)(sqv + 2048 + 16);              // [2048,256]
    unsigned short* hn_bf = (unsigned short*)(sqv + 2048 + 16 + 524288);  // [2048,256]
    unsigned short* q_bf  = hn_bf + 524288;
    unsigned short* k_bf  = q_bf + 524288;
    unsigned short* vt_bf = k_bf + 524288;    // [8,8,32,256] = [b,h,d,j]
    unsigned short* ao_bf = vt_bf + 524288;   // [2048,256]
    unsigned short* fm_bf = ao_bf + 524288;   // [2048,512]
    unsigned short* wtb   = fm_bf + 1048576;  // [2][524288]
    unsigned short* w2b   = wtb + 1048576;    // 256*256*384 bf16 = 50.3 MB

    init_kernel<<<2048, 256, 0, stream>>>(dmax, cnnmax);
    prep_wt_kernel<<<dim3(16, 16, 12), 256, 0, stream>>>(wq, wk, wvp, wo, ffn_w1, ffn_w2, wtb);
    prep_w2_kernel<<<dim3(256, 4), 256, 0, stream>>>(conv2_w, w2b);
    conv2_fused_kernel<<<dim3(256, 16), 512, 0, stream>>>(
        w2b, x, conv1_w, conv1_b, conv2_b, cnnmax);
    ln0_kernel<<<512, 256, 0, stream>>>(cnnmax, h, sqv);
    dist_kernel<<<1024, 256, 0, stream>>>(h, sqv, dist, dmax);

    for (int l = 0; l < 2; l++) {
        const unsigned short* wqkvT = wtb + (size_t)l * 524288;
        const unsigned short* woT   = wqkvT + 196608;
        const unsigned short* f1T   = wqkvT + 262144;
        const unsigned short* f2T   = wqkvT + 393216;

        ln_bf_kernel<<<512, 256, 0, stream>>>(h, ln1_g + l * 256, ln1_b + l * 256, hn_bf);
        gemm_mfma_kernel<<<dim3(16, 24), 128, 0, stream>>>(
            hn_bf, wqkvT, bq + l * 256, bk + l * 256, bv + l * 256,
            nullptr, nullptr, q_bf, k_bf, vt_bf, 256, 0);
        attn_mfma_kernel<<<dim3(4, 8, 8), 256, 0, stream>>>(
            q_bf, k_bf, vt_bf, dist, dmax, bias_w + l * 32, bias_b + l * 8, ao_bf);
        gemm_mfma_kernel<<<dim3(16, 8), 128, 0, stream>>>(
            ao_bf, woT, bo + l * 256, nullptr, nullptr,
            h, h, nullptr, nullptr, nullptr, 256, 1);
        ln_bf_kernel<<<512, 256, 0, stream>>>(h, ln2_g + l * 256, ln2_b + l * 256, hn_bf);
        gemm_mfma_kernel<<<dim3(16, 16), 128, 0, stream>>>(
            hn_bf, f1T, ffn_b1 + l * 512, nullptr, nullptr,
            nullptr, nullptr, fm_bf, nullptr, nullptr, 256, 2);
        gemm_mfma_kernel<<<dim3(16, 8), 128, 0, stream>>>(
            fm_bf, f2T, ffn_b2 + l * 256, nullptr, nullptr,
            h, h, nullptr, nullptr, nullptr, 512, 1);
    }
    pool_fc_kernel<<<8, 256, 0, stream>>>(h, fc_w, fc_b, out);
}